// Round 1
// 423.007 us; speedup vs baseline: 1.0531x; 1.0531x over previous
//
#include <hip/hip_runtime.h>

#define DHW   192
#define DHW2  (DHW*DHW)
#define TX    64           // lanes span x (one wave = one row of 64 x)
#define TTY   4            // ty rows of threads
#define YB    4            // outputs per thread in y
#define BY    (TTY*YB)     // 16  block y-tile
#define ZCH   16           // z per block
#define NT    (TX*TTY)     // 256 threads
#define RY    (BY+4)       // 20  ring rows (y halo 2)
#define RXW   (TX+8)       // 72  ring row width (x halo 4 for float4 alignment)
#define SLICE (RY*RXW)     // 1440 floats per slice
#define NF4   (SLICE/4)    // 360 float4 groups
#define ROWF4 (RXW/4)      // 18

__global__ __launch_bounds__(NT)
void mind3d_kernel(const float* __restrict__ img, float* __restrict__ out)
{
    __shared__ float ring[4][SLICE];      // 23 KB: 4-deep z-ring of img slices

    const int lane = threadIdx.x;
    const int ty   = threadIdx.y;
    const int tid  = ty*TX + lane;

    const int x0 = blockIdx.x * TX;
    const int y0 = blockIdx.y * BY;
    const int zi = blockIdx.z;
    const int nzc = DHW / ZCH;            // 12
    const int b  = zi / nzc;
    const int z0 = (zi - b*nzc) * ZCH;

    const float* imgb = img + (size_t)b * ((size_t)DHW * DHW2);

    const float a1 = 0.01831563889245986f;     // exp(-1/sigma^2)
    const float n1 = 1.0f/(1.0f + 2.0f*a1);
    const float norm3 = n1*n1*n1;

    const int gx = x0 + lane;
    const float mL = (gx == 0)     ? 0.f : 1.f;   // conv zero-pad mask at x=-1
    const float mR = (gx == DHW-1) ? 0.f : 1.f;   // conv zero-pad mask at x=192
    const int wy = y0 + ty*YB;                    // first output row of this thread
    const int u  = lane + 4;                      // ring column of this thread's x

    auto load_slice = [&](int z) {
        float4* dst = (float4*)ring[(z + 8) & 3];   // slot = z mod 4
        if ((unsigned)z >= (unsigned)DHW) {
            for (int g = tid; g < NF4; g += NT)
                dst[g] = float4{0.f, 0.f, 0.f, 0.f};
        } else {
            const float* sp = imgb + (size_t)z * DHW2;
            for (int g = tid; g < NF4; g += NT) {
                int row = g / ROWF4;
                int c4  = g - row*ROWF4;
                int gy  = y0 - 2 + row;
                int gxs = x0 - 16/4*4 + (c4 << 2) + (16/4*4 - 4); // = x0 - 4 + 4*c4
                float4 v = {0.f, 0.f, 0.f, 0.f};
                // groups are 4-aligned in x -> fully in or fully out of [0,192)
                if ((unsigned)gy < (unsigned)DHW && (unsigned)gxs <= (unsigned)(DHW - 4))
                    v = *(const float4*)(sp + (size_t)gy*DHW + gxs);
                dst[g] = v;
            }
        }
    };

    // z-direction register ring of smoothed slices per output row
    float zm[YB][6], zc[YB][6];
    #pragma unroll
    for (int j = 0; j < YB; ++j)
        #pragma unroll
        for (int c = 0; c < 6; ++c) { zm[j][c] = 0.f; zc[j][c] = 0.f; }

    load_slice(z0 - 2);
    load_slice(z0 - 1);
    load_slice(z0);
    __syncthreads();

    for (int zs = z0 - 1; zs <= z0 + ZCH; ++zs) {
        // stage slice zs+2 (4-deep ring: overwrites zs-2, untouched this step)
        if (zs < z0 + ZCH) load_slice(zs + 2);

        const bool zok = ((unsigned)zs < (unsigned)DHW);
        const float* rcs = ring[(zs + 8) & 3] + ty*YB*RXW + u;        // row wy-2
        const float* rps = ring[(zs + 9) & 3] + (ty*YB + 1)*RXW + u;  // row wy-1
        const float* rms = ring[(zs + 7) & 3] + (ty*YB + 1)*RXW + u;

        // 3-row register window of center-slice rows (5 cols: x-2..x+2)
        float A0,A1,A2,A3,A4, B0,B1,B2,B3,B4;
        A0 = rcs[-2];     A1 = rcs[-1];     A2 = rcs[0];   A3 = rcs[1];     A4 = rcs[2];
        B0 = rcs[RXW-2];  B1 = rcs[RXW-1];  B2 = rcs[RXW]; B3 = rcs[RXW+1]; B4 = rcs[RXW+2];

        float T[3][6];                     // rotating x-conv rows (all indices static)
        const int zcout = zs - 1;
        const bool emitz = (zcout >= z0);

        #pragma unroll
        for (int k = 0; k < 6; ++k) {      // T rows wy-1 .. wy+4
            const int gr = wy - 1 + k;
            const float* rk = rcs + (k + 2)*RXW;      // center row gr+1
            float C0 = rk[-2], C1 = rk[-1], C2 = rk[0], C3 = rk[1], C4 = rk[2];
            const float* pk = rps + k*RXW;            // z+1 slice, row gr
            const float* mk = rms + k*RXW;            // z-1 slice, row gr
            float zpL = pk[-1], zpC = pk[0], zpR = pk[1];
            float zmL = mk[-1], zmC = mk[0], zmR = mk[1];

            const bool rok = zok && ((unsigned)gr < (unsigned)DHW);
            if (rok) {
                // x-channel shared diffs over cols x-2..x+2
                float d0 = B1-B0, d1 = B2-B1, d2 = B3-B2, d3 = B4-B3;
                float q0 = d0*d0, q1 = d1*d1, q2 = d2*d2, q3 = d3*d3;
                float eL, eC, eR;
                eL = zpL-B1; eC = zpC-B2; eR = zpR-B3;                       // +z
                T[k%3][0] = a1*(eL*eL*mL + eR*eR*mR) + eC*eC;
                eL = zmL-B1; eC = zmC-B2; eR = zmR-B3;                       // -z
                T[k%3][1] = a1*(eL*eL*mL + eR*eR*mR) + eC*eC;
                eL = C1-B1;  eC = C2-B2;  eR = C3-B3;                        // +y
                T[k%3][2] = a1*(eL*eL*mL + eR*eR*mR) + eC*eC;
                eL = A1-B1;  eC = A2-B2;  eR = A3-B3;                        // -y
                T[k%3][3] = a1*(eL*eL*mL + eR*eR*mR) + eC*eC;
                T[k%3][4] = a1*(q1*mL + q3*mR) + q2;                         // +x
                T[k%3][5] = a1*(q0*mL + q2*mR) + q1;                         // -x
            } else {
                #pragma unroll
                for (int c = 0; c < 6; ++c) T[k%3][c] = 0.f;
            }

            if (k >= 2) {
                const int j = k - 2;       // output row wy+j ready
                float sp_[6];
                #pragma unroll
                for (int c = 0; c < 6; ++c)
                    sp_[c] = a1*(T[(k-2)%3][c] + T[k%3][c]) + T[(k-1)%3][c]; // y-conv
                if (emitz) {
                    float dp[6], sum = 0.f;
                    #pragma unroll
                    for (int c = 0; c < 6; ++c) {
                        dp[c] = norm3 * (a1*(zm[j][c] + sp_[c]) + zc[j][c]); // z-conv
                        sum += dp[c];
                    }
                    float inv = 1.0f / (sum * (1.0f/6.0f) + 1e-8f);
                    float num[6], nsum = 0.f;
                    #pragma unroll
                    for (int c = 0; c < 6; ++c) {
                        num[c] = __expf(-dp[c] * inv);
                        nsum += num[c];
                    }
                    float rs = 1.0f / (nsum + 1e-8f);
                    size_t base = ((size_t)(6*b)*DHW + zcout) * (size_t)DHW2
                                + (size_t)(wy + j)*DHW + (size_t)gx;
                    #pragma unroll
                    for (int c = 0; c < 6; ++c)
                        out[base + (size_t)c * ((size_t)DHW*DHW2)] = num[c]*rs;
                }
                #pragma unroll
                for (int c = 0; c < 6; ++c) { zm[j][c] = zc[j][c]; zc[j][c] = sp_[c]; }
            }
            // shift row window (register renames after unroll, ~free)
            A0=B0; A1=B1; A2=B2; A3=B3; A4=B4;
            B0=C0; B1=C1; B2=C2; B3=C3; B4=C4;
        }
        __syncthreads();    // single barrier per z-step
    }
}

extern "C" void kernel_launch(void* const* d_in, const int* in_sizes, int n_in,
                              void* d_out, int out_size, void* d_ws, size_t ws_size,
                              hipStream_t stream)
{
    const float* img = (const float*)d_in[0];
    float* out = (float*)d_out;
    dim3 block(TX, TTY, 1);
    dim3 grid(DHW/TX, DHW/BY, 2*(DHW/ZCH));   // 3 x 12 x 24 = 864 blocks
    hipLaunchKernelGGL(mind3d_kernel, grid, block, 0, stream, img, out);
}

// Round 4
// 410.196 us; speedup vs baseline: 1.0860x; 1.0312x over previous
//
#include <hip/hip_runtime.h>

#define DHW   192
#define DHW2  (DHW*DHW)
#define TX    64           // lanes span x (one wave = one x-row)
#define TTY   4
#define YB    4            // output rows per thread
#define BY    (TTY*YB)     // 16
#define ZCH   8            // 1728 blocks -> CU balance + latency hiding
#define NT    (TX*TTY)     // 256
#define RY    (BY+4)       // 20
#define RXW   (TX+8)       // 72
#define SLICE (RY*RXW)     // 1440
#define NF4   (SLICE/4)    // 360
#define ROWF4 (RXW/4)      // 18

__global__ __launch_bounds__(NT, 4)   // 4 blocks/CU co-resident (VGPR<=128)
void mind3d_kernel(const float* __restrict__ img, float* __restrict__ out)
{
    __shared__ float ring[4][SLICE];   // 23 KB, 4-deep z-ring

    const int lane = threadIdx.x;
    const int ty   = threadIdx.y;
    const int tid  = ty*TX + lane;

    const int x0 = blockIdx.x * TX;
    const int y0 = blockIdx.y * BY;
    const int zi = blockIdx.z;
    const int nzc = DHW / ZCH;          // 24
    const int b  = zi / nzc;
    const int z0 = (zi - b*nzc) * ZCH;

    const float* imgb = img + (size_t)b * ((size_t)DHW * DHW2);

    const float a1 = 0.01831563889245986f;   // exp(-1/sigma^2)
    const float n1 = 1.0f/(1.0f + 2.0f*a1);
    const float norm3 = n1*n1*n1;

    const int gx = x0 + lane;
    const float mL = (gx == 0)     ? 0.f : 1.f;
    const float mR = (gx == DHW-1) ? 0.f : 1.f;
    const int wy = y0 + ty*YB;
    const int u  = lane + 4;

    // ---- staging coords (z-independent) ----
    const int r0  = tid / ROWF4, c0i = tid - r0*ROWF4;
    const int gy0s = y0 - 2 + r0, gx0s = x0 - 4 + (c0i << 2);
    const bool in0 = ((unsigned)gy0s < (unsigned)DHW) && ((unsigned)gx0s <= (unsigned)(DHW-4));
    const int t2  = tid + NT;
    const bool g2 = (t2 < NF4);
    const int r1  = t2 / ROWF4, c1i = t2 - r1*ROWF4;
    const int gy1s = y0 - 2 + r1, gx1s = x0 - 4 + (c1i << 2);
    const bool in1 = g2 && ((unsigned)gy1s < (unsigned)DHW) && ((unsigned)gx1s <= (unsigned)(DHW-4));

    float4 sv0, sv1;   // in-flight staged slice (T14: issue early, write late)
    auto issue = [&](int z) {
        sv0 = float4{0.f,0.f,0.f,0.f};
        sv1 = float4{0.f,0.f,0.f,0.f};
        if ((unsigned)z < (unsigned)DHW) {
            const float* sp = imgb + (size_t)z * DHW2;
            if (in0) sv0 = *(const float4*)(sp + (size_t)gy0s*DHW + gx0s);
            if (in1) sv1 = *(const float4*)(sp + (size_t)gy1s*DHW + gx1s);
        }
    };
    auto commit = [&](int z) {
        float4* dst = (float4*)ring[(z + 8) & 3];
        dst[tid] = sv0;
        if (g2) dst[t2] = sv1;
    };

    // z-direction register state: smoothed S at z-1 (zm), z (zc), + ch0 carry
    float zm[YB][6], zc[YB][6], zS0[YB];
    #pragma unroll
    for (int j = 0; j < YB; ++j) {
        zS0[j] = 0.f;
        #pragma unroll
        for (int c = 0; c < 6; ++c) { zm[j][c] = 0.f; zc[j][c] = 0.f; }
    }

    // prologue: slices z0-2..z0 resident; z0+1 in flight
    issue(z0-2); commit(z0-2);
    issue(z0-1); commit(z0-1);
    issue(z0);   commit(z0);
    issue(z0+1);
    __syncthreads();

    for (int zs = z0 - 1; zs <= z0 + ZCH; ++zs) {
        // write staged slice zs+2 (issued one full step ago); slot disjoint
        // from this step's read slots {zs-1, zs, zs+1} mod 4
        if (zs + 2 <= z0 + ZCH + 1) commit(zs + 2);
        if (zs + 3 <= z0 + ZCH + 1) issue(zs + 3);

        const bool zok  = ((unsigned)zs < (unsigned)DHW);
        const bool warm = (zs == z0 - 1);      // only step with explicit ch1 (-z)
        const float* rcs = ring[(zs + 8) & 3] + ty*YB*RXW + u;        // center slice
        const float* rps = ring[(zs + 9) & 3] + (ty*YB + 1)*RXW + u;  // z+1 slice
        const float* rms = ring[(zs + 7) & 3] + (ty*YB + 1)*RXW + u;  // z-1 (warm only)

        float A1 = rcs[-1], A2 = rcs[0], A3 = rcs[1];
        float B0 = rcs[RXW-2], B1 = rcs[RXW-1], B2 = rcs[RXW], B3 = rcs[RXW+1], B4 = rcs[RXW+2];

        float T[3][6];                          // rotating x-conv rows, static indices
        const int zcout = zs - 1;
        const bool emitz = (zcout >= z0);

        #pragma unroll
        for (int k = 0; k < 6; ++k) {
            const int gr = wy - 1 + k;
            const float* rk = rcs + (k + 2)*RXW;
            float C0 = rk[-2], C1 = rk[-1], C2 = rk[0], C3 = rk[1], C4 = rk[2];
            const float* pk = rps + k*RXW;
            float zpL = pk[-1], zpC = pk[0], zpR = pk[1];

            const bool rowok = ((unsigned)gr < (unsigned)DHW);
            const bool rok   = zok && rowok;
            float* Tk = T[k % 3];

            // +z channel: gate by ROW only (raw form feeds the ch1 carry).
            // Out-of-volume ring slices hold zeros, so at zs=-1 this yields
            // x-smooth(img(0)^2) (= E1(0) pre-smooth), at zs=192 it yields 0.
            {
                float eL = zpL-B1, eC = zpC-B2, eR = zpR-B3;
                Tk[0] = rowok ? (a1*(eL*eL*mL + eR*eR*mR) + eC*eC) : 0.f;
            }
            if (rok) {
                float d0 = B1-B0, d1 = B2-B1, d2 = B3-B2, d3 = B4-B3;
                float q0 = d0*d0, q1 = d1*d1, q2 = d2*d2, q3 = d3*d3;
                float eL, eC, eR;
                eL = C1-B1;  eC = C2-B2;  eR = C3-B3;                       // +y
                Tk[2] = a1*(eL*eL*mL + eR*eR*mR) + eC*eC;
                eL = A1-B1;  eC = A2-B2;  eR = A3-B3;                       // -y
                Tk[3] = a1*(eL*eL*mL + eR*eR*mR) + eC*eC;
                Tk[4] = a1*(q1*mL + q3*mR) + q2;                            // +x
                Tk[5] = a1*(q0*mL + q2*mR) + q1;                            // -x
            } else {
                Tk[2]=0.f; Tk[3]=0.f; Tk[4]=0.f; Tk[5]=0.f;
            }
            if (warm) {                        // explicit -z channel, first step only
                float t1v = 0.f;
                if (rok) {
                    const float* mk = rms + k*RXW;
                    float zmL = mk[-1], zmC = mk[0], zmR = mk[1];
                    float eL = zmL-B1, eC = zmC-B2, eR = zmR-B3;
                    t1v = a1*(eL*eL*mL + eR*eR*mR) + eC*eC;
                }
                Tk[1] = t1v;
            }

            if (k >= 2) {
                const int j = k - 2;           // output row wy+j
                // raw s0: row-gated only; feeds the ch1 carry (S1(zs+1)=S0(zs))
                float s0 = a1*(T[(k-2)%3][0] + T[k%3][0]) + T[(k-1)%3][0];
                float s2 = a1*(T[(k-2)%3][2] + T[k%3][2]) + T[(k-1)%3][2];
                float s3 = a1*(T[(k-2)%3][3] + T[k%3][3]) + T[(k-1)%3][3];
                float s4 = a1*(T[(k-2)%3][4] + T[k%3][4]) + T[(k-1)%3][4];
                float s5 = a1*(T[(k-2)%3][5] + T[k%3][5]) + T[(k-1)%3][5];
                // S-carry for ch1; at zs==DHW force conv zero-pad (0)
                float s1 = warm ? (a1*(T[(k-2)%3][1] + T[k%3][1]) + T[(k-1)%3][1])
                                : (zok ? zS0[j] : 0.f);
                zS0[j] = s0;
                // ch0's OWN z-state must see S0==0 outside [0,DHW): at zs=-1 the
                // raw s0 = smooth(img0^2) is carry-fuel only, NOT state.
                float s0st = zok ? s0 : 0.f;
                float sp_[6] = {s0st, s1, s2, s3, s4, s5};

                if (emitz) {
                    float dp[6], sum = 0.f;
                    #pragma unroll
                    for (int c = 0; c < 6; ++c) {
                        dp[c] = norm3 * (a1*(zm[j][c] + sp_[c]) + zc[j][c]);
                        sum += dp[c];
                    }
                    float inv = 1.0f / (sum * (1.0f/6.0f) + 1e-8f);
                    float num[6], nsum = 0.f;
                    #pragma unroll
                    for (int c = 0; c < 6; ++c) {
                        num[c] = __expf(-dp[c] * inv);
                        nsum += num[c];
                    }
                    float rs = 1.0f / (nsum + 1e-8f);
                    size_t base = ((size_t)(6*b)*DHW + zcout) * (size_t)DHW2
                                + (size_t)(wy + j)*DHW + (size_t)gx;
                    #pragma unroll
                    for (int c = 0; c < 6; ++c)
                        out[base + (size_t)c * ((size_t)DHW*DHW2)] = num[c]*rs;
                }
                #pragma unroll
                for (int c = 0; c < 6; ++c) { zm[j][c] = zc[j][c]; zc[j][c] = sp_[c]; }
            }
            A1=B1; A2=B2; A3=B3;
            B0=C0; B1=C1; B2=C2; B3=C3; B4=C4;
        }
        __syncthreads();   // single barrier per z-step
    }
}

extern "C" void kernel_launch(void* const* d_in, const int* in_sizes, int n_in,
                              void* d_out, int out_size, void* d_ws, size_t ws_size,
                              hipStream_t stream)
{
    const float* img = (const float*)d_in[0];
    float* out = (float*)d_out;
    dim3 block(TX, TTY, 1);
    dim3 grid(DHW/TX, DHW/BY, 2*(DHW/ZCH));   // 3 x 12 x 48 = 1728 blocks
    hipLaunchKernelGGL(mind3d_kernel, grid, block, 0, stream, img, out);
}